// Round 8
// baseline (19.949 us; speedup 1.0000x reference)
//
#include <hip/hip_runtime.h>

// GCNCountry: out = ((leaky(leaky(adj@(x@Wgc)+bgc) @ W1 + b1) * dropmask) @ W2 + b2)[0]
// -> depends ONLY on row 0 of every intermediate. Vector chain:
//    v  = adj[0,:] @ x            (16 MB x-read, K1, 256 blocks -> 32 partials)
//    h0 = v @ Wgc; h1 = leaky(h0+bgc) @ W1; out = dropout(leaky(h1+b1)).W2+b2
//       -> K23: 64 blocks, one k-chunk of 16 each (no j-split, no redundancy),
//          per-block footprint 128KB (was 192KB at 32 blocks); last-arriving
//          block finalizes (t0-only release/acquire, R6-proven).
//
// Cost model (R1-R7): harness fixed ~10-12us; node gap ~0.5-1us; spin grid
// barrier ~10us (never); per-thread agent fences bad (R5); t0-only last-arrive
// ~free (R6); register mega-preloads neutral-to-worse than LDS staging (R7);
// K23 is per-CU-BW bound -> more blocks with smaller footprints.

constexpr int N_FEAT  = 512;
constexpr int N_HID1  = 1024;
constexpr int N_HID2  = 512;
constexpr float SLOPE  = 0.01f;
constexpr float DROP_P = 0.3f;

constexpr int VP_N   = 32;      // v partials [32][512]
constexpr int VP_OFF = 0;
constexpr int H1_OFF = 16384;   // h1 partials [64][512]
constexpr int CNT_OFF = 49152;  // 1 int, zeroed by K1 each call
constexpr int NBLK2  = 64;      // K23 grid: 64 k-chunks of 16

__device__ __forceinline__ float leaky(float x) { return x >= 0.f ? x : SLOPE * x; }

// ---------------- K1: v_part[rb][c] = sum_{rows in chunk rb} adj0[row] * x[row][c] ----------------
// grid (8 col-stripes of 64, 32 row-chunks of 256), 256 thr; float4 fully-coalesced x reads.
__global__ __launch_bounds__(256) void k1_adjrow_x(const float* __restrict__ x,
                                                   const float* __restrict__ adj0,
                                                   float* __restrict__ vp,
                                                   int* __restrict__ cnt) {
    const int tid = threadIdx.x;
    if (blockIdx.x == 0 && blockIdx.y == 0 && tid == 0) cnt[0] = 0;  // visible at kernel boundary

    const int f4  = tid & 15;
    const int r   = tid >> 4;          // 0..15
    const int c0  = blockIdx.x * 64;   // col stripe
    const int rb  = blockIdx.y;        // row chunk
    const float4* x4 = reinterpret_cast<const float4*>(x);

    float4 acc = {0.f, 0.f, 0.f, 0.f};
    int row = rb * 256 + r;
    #pragma unroll
    for (int it = 0; it < 16; ++it, row += 16) {
        const float  a  = adj0[row];
        const float4 xv = x4[row * (N_FEAT / 4) + (c0 >> 2) + f4];
        acc.x = fmaf(a, xv.x, acc.x);
        acc.y = fmaf(a, xv.y, acc.y);
        acc.z = fmaf(a, xv.z, acc.z);
        acc.w = fmaf(a, xv.w, acc.w);
    }

    __shared__ float4 sm[256];
    sm[tid] = acc;
    __syncthreads();
    #pragma unroll
    for (int off = 128; off >= 16; off >>= 1) {
        if (tid < off) {
            float4 o = sm[tid + off];
            sm[tid].x += o.x; sm[tid].y += o.y; sm[tid].z += o.z; sm[tid].w += o.w;
        }
        __syncthreads();
    }
    if (tid < 16)
        reinterpret_cast<float4*>(vp + rb * N_FEAT + c0)[tid] = sm[tid];
}

// ---------------- K23: one k-chunk of 16 per block; LDS staging; last-arrive finalize ----------------
__global__ __launch_bounds__(256, 1) void k23_fused(const float* __restrict__ vp,
                                                    const float* __restrict__ Wgc,
                                                    const float* __restrict__ bgc,
                                                    const float* __restrict__ W1,
                                                    const float* __restrict__ b1,
                                                    const float* __restrict__ W2,
                                                    const float* __restrict__ b2,
                                                    const float* __restrict__ du0,
                                                    float* __restrict__ h1p,
                                                    int* __restrict__ cnt,
                                                    float* __restrict__ out) {
    const int t  = threadIdx.x;
    const int kc = blockIdx.x;          // 0..63
    const int k0 = kc * 16;             // h0-chunk [k0, k0+16)

    __shared__ float4 va[128];          // phase-A scratch
    __shared__ float4 vl4[128];         // full v (512 floats)
    __shared__ float  smb[64][17];      // phase-B m-group partials (padded)
    __shared__ float  hl[16];           // leaky(h0+bgc) chunk

    // ---- Phase A: v = sum of 32 partials (float4, 2 p-halves, one latency exposure) ----
    {
        const float4* vp4 = reinterpret_cast<const float4*>(vp);
        const int slot = t & 127;
        const int ph   = t >> 7;        // 0,1
        float4 a = {0.f, 0.f, 0.f, 0.f};
        #pragma unroll
        for (int p = 0; p < 16; ++p) {
            const float4 xv = vp4[(ph * 16 + p) * 128 + slot];
            a.x += xv.x; a.y += xv.y; a.z += xv.z; a.w += xv.w;
        }
        if (ph == 0) va[slot] = a;
        __syncthreads();
        if (ph == 1) {
            float4 o = va[slot];
            o.x += a.x; o.y += a.y; o.z += a.z; o.w += a.w;
            vl4[slot] = o;
        }
        __syncthreads();
    }
    const float* vl = reinterpret_cast<const float*>(vl4);

    // ---- Phase B: h0[k0..k0+16) = v @ Wgc[:, chunk]; 64 m-groups x 4 float4 k-quads ----
    {
        const float4* Wgc4 = reinterpret_cast<const float4*>(Wgc);
        const int q  = t & 3;           // k-quad 0..3 (4 k each)
        const int mg = t >> 2;          // m-group 0..63
        float4 acc = {0.f, 0.f, 0.f, 0.f};
        #pragma unroll
        for (int p = 0; p < 8; ++p) {
            const int m = p * 64 + mg;  // stride-64 rows: coalesced across mg
            const float4 w = Wgc4[m * (N_HID1 / 4) + (k0 >> 2) + q];
            const float vm = vl[m];
            acc.x = fmaf(vm, w.x, acc.x);
            acc.y = fmaf(vm, w.y, acc.y);
            acc.z = fmaf(vm, w.z, acc.z);
            acc.w = fmaf(vm, w.w, acc.w);
        }
        smb[mg][q * 4 + 0] = acc.x;
        smb[mg][q * 4 + 1] = acc.y;
        smb[mg][q * 4 + 2] = acc.z;
        smb[mg][q * 4 + 3] = acc.w;
        __syncthreads();
        if (t < 16) {
            float s = bgc[k0 + t];
            #pragma unroll
            for (int g = 0; g < 64; ++g) s += smb[g][t];
            hl[t] = leaky(s);
        }
        __syncthreads();
    }

    // ---- Phase C: h1 partial row (512 j, float2/thread) ----
    {
        float2 acc = {0.f, 0.f};
        #pragma unroll
        for (int k = 0; k < 16; ++k) {
            const float2 w = *reinterpret_cast<const float2*>(&W1[(k0 + k) * N_HID2 + 2 * t]);
            acc.x = fmaf(hl[k], w.x, acc.x);
            acc.y = fmaf(hl[k], w.y, acc.y);
        }
        *reinterpret_cast<float2*>(&h1p[kc * N_HID2 + 2 * t]) = acc;
    }

    // ---- last-arrive: t0-only release; only the 64th block pays an acquire ----
    __shared__ int amLast;
    __syncthreads();   // drains this block's h1p stores (vmcnt(0) before s_barrier)
    if (t == 0) {
        int old = __hip_atomic_fetch_add(cnt, 1, __ATOMIC_RELEASE, __HIP_MEMORY_SCOPE_AGENT);
        amLast = (old == NBLK2 - 1);
    }
    __syncthreads();
    if (!amLast) return;
    if (t == 0)  // single acquire: make all blocks' h1p stores visible
        (void)__hip_atomic_load(cnt, __ATOMIC_ACQUIRE, __HIP_MEMORY_SCOPE_AGENT);
    __syncthreads();

    // ---- Phase D: reduce 64 h1 partials, bias+leaky+dropout, dot W2[:,0], +b2 ----
    {
        const float2 pb1 = *reinterpret_cast<const float2*>(&b1[2 * t]);
        const float2 pW2 = *reinterpret_cast<const float2*>(&W2[2 * t]);
        const float2 pdu = *reinterpret_cast<const float2*>(&du0[2 * t]);
        float s0 = pb1.x, s1 = pb1.y;
        #pragma unroll
        for (int p = 0; p < NBLK2; ++p) {
            const float2 hp = *reinterpret_cast<const float2*>(&h1p[p * N_HID2 + 2 * t]);
            s0 += hp.x; s1 += hp.y;
        }
        float ha = leaky(s0), hb = leaky(s1);
        ha = (pdu.x >= DROP_P) ? ha / (1.0f - DROP_P) : 0.f;
        hb = (pdu.y >= DROP_P) ? hb / (1.0f - DROP_P) : 0.f;
        float term = fmaf(ha, pW2.x, hb * pW2.y);

        #pragma unroll
        for (int off = 32; off; off >>= 1) term += __shfl_down(term, off, 64);
        __shared__ float red[4];
        if ((t & 63) == 0) red[t >> 6] = term;
        __syncthreads();
        if (t == 0)
            out[0] = red[0] + red[1] + red[2] + red[3] + b2[0];
    }
}

extern "C" void kernel_launch(void* const* d_in, const int* in_sizes, int n_in,
                              void* d_out, int out_size, void* d_ws, size_t ws_size,
                              hipStream_t stream) {
    const float* x   = (const float*)d_in[0];
    const float* adj = (const float*)d_in[1];  // row 0 = first 8192 floats
    const float* Wgc = (const float*)d_in[2];
    const float* bgc = (const float*)d_in[3];
    const float* W1  = (const float*)d_in[4];
    const float* b1  = (const float*)d_in[5];
    const float* W2  = (const float*)d_in[6];
    const float* b2  = (const float*)d_in[7];
    const float* du  = (const float*)d_in[8];  // row 0 = first 512 floats
    float* out = (float*)d_out;
    float* ws  = (float*)d_ws;

    float* vp  = ws + VP_OFF;
    float* h1p = ws + H1_OFF;
    int*   cnt = (int*)(ws + CNT_OFF);

    k1_adjrow_x<<<dim3(8, 32), 256, 0, stream>>>(x, adj, vp, cnt);
    k23_fused  <<<dim3(NBLK2), 256, 0, stream>>>(vp, Wgc, bgc, W1, b1, W2, b2, du,
                                                 h1p, cnt, out);
}

// Round 9
// 16.558 us; speedup vs baseline: 1.2048x; 1.2048x over previous
//
#include <hip/hip_runtime.h>

// GCNCountry: out = ((leaky(leaky(adj@(x@Wgc)+bgc) @ W1 + b1) * dropmask) @ W2 + b2)[0]
// -> depends ONLY on row 0 of every intermediate. Vector chain:
//    v  = adj[0,:] @ x            (16 MB x-read, K1, 256 blocks -> 32 partials)
//    h0 = v @ Wgc; h1 = leaky(h0+bgc) @ W1; out = dropout(leaky(h1+b1)).W2+b2
//       -> ALL fused in K23 (32 blocks): each block redundantly computes its own
//          64-wide h0 chunk (2x read of L3-resident Wgc, ~free), h1 partial,
//          then t0-only RELEASE fetch_add; last-arriving block finalizes.
//
// FINAL (round 9 = revert to round-6 best, 16.61us measured):
// Cost model from rounds 1-8: harness/graph fixed overhead ~10-12us; in-graph
// node gap ~1us; K1 ~2.5-3us (16MB stream, near BW limit); K23 ~3us.
// Measured-and-rejected alternatives: spin grid-barrier (+10us, R3);
// deep-k few-block kernels (latency-bound, R4); per-thread agent fences
// (R5); register mega-preloads (neutral, R7); 64 small blocks (worse vp
// reuse + serial reduces, R8). This 2-node shape is the structural floor.

constexpr int N_FEAT  = 512;
constexpr int N_HID1  = 1024;
constexpr int N_HID2  = 512;
constexpr float SLOPE  = 0.01f;
constexpr float DROP_P = 0.3f;

constexpr int VP_N   = 32;      // v partials [32][512]
constexpr int VP_OFF = 0;
constexpr int H1_OFF = 16384;   // h1 partials [16][512]
constexpr int CNT_OFF = 24576;  // 1 int, zeroed by K1 each call
constexpr int NBLK2  = 32;      // K23 grid

__device__ __forceinline__ float leaky(float x) { return x >= 0.f ? x : SLOPE * x; }

// ---------------- K1: v_part[rb][c] = sum_{rows in chunk rb} adj0[row] * x[row][c] ----------------
// grid (8 col-stripes of 64, 32 row-chunks of 256), 256 thr; float4 fully-coalesced x reads.
__global__ __launch_bounds__(256) void k1_adjrow_x(const float* __restrict__ x,
                                                   const float* __restrict__ adj0,
                                                   float* __restrict__ vp,
                                                   int* __restrict__ cnt) {
    const int tid = threadIdx.x;
    if (blockIdx.x == 0 && blockIdx.y == 0 && tid == 0) cnt[0] = 0;  // visible at kernel boundary

    const int f4  = tid & 15;
    const int r   = tid >> 4;          // 0..15
    const int c0  = blockIdx.x * 64;   // col stripe
    const int rb  = blockIdx.y;        // row chunk
    const float4* x4 = reinterpret_cast<const float4*>(x);

    float4 acc = {0.f, 0.f, 0.f, 0.f};
    int row = rb * 256 + r;
    #pragma unroll
    for (int it = 0; it < 16; ++it, row += 16) {
        const float  a  = adj0[row];
        const float4 xv = x4[row * (N_FEAT / 4) + (c0 >> 2) + f4];
        acc.x = fmaf(a, xv.x, acc.x);
        acc.y = fmaf(a, xv.y, acc.y);
        acc.z = fmaf(a, xv.z, acc.z);
        acc.w = fmaf(a, xv.w, acc.w);
    }

    __shared__ float4 sm[256];
    sm[tid] = acc;
    __syncthreads();
    #pragma unroll
    for (int off = 128; off >= 16; off >>= 1) {
        if (tid < off) {
            float4 o = sm[tid + off];
            sm[tid].x += o.x; sm[tid].y += o.y; sm[tid].z += o.z; sm[tid].w += o.w;
        }
        __syncthreads();
    }
    if (tid < 16)
        reinterpret_cast<float4*>(vp + rb * N_FEAT + c0)[tid] = sm[tid];
}

// ---------------- K23: redundant h0 chunk + h1 partial + last-arrive finalize ----------------
// 32 blocks = (jb = bid&1: j-half of 256) x (kc = bid>>1: k-chunk of 64).
__global__ __launch_bounds__(256, 1) void k23_fused(const float* __restrict__ vp,
                                                    const float* __restrict__ Wgc,
                                                    const float* __restrict__ bgc,
                                                    const float* __restrict__ W1,
                                                    const float* __restrict__ b1,
                                                    const float* __restrict__ W2,
                                                    const float* __restrict__ b2,
                                                    const float* __restrict__ du0,
                                                    float* __restrict__ h1p,
                                                    int* __restrict__ cnt,
                                                    float* __restrict__ out) {
    const int t  = threadIdx.x;
    const int jb = blockIdx.x & 1;
    const int kc = blockIdx.x >> 1;
    const int k0 = kc * 64;

    __shared__ float4 vl4[128];      // full v (512 floats)
    __shared__ float4 va[128];       // phase-A scratch
    __shared__ float  hl[64];        // leaky(h0+bgc) chunk
    __shared__ float  smb[16][65];   // phase-B partial reduce (padded)

    // ---- Phase A: v = sum of 32 partials (float4, 2 p-halves, one latency exposure) ----
    {
        const float4* vp4 = reinterpret_cast<const float4*>(vp);
        const int slot = t & 127;
        const int ph   = t >> 7;     // 0,1
        float4 a = {0.f, 0.f, 0.f, 0.f};
        #pragma unroll
        for (int p = 0; p < 16; ++p) {
            const float4 xv = vp4[(ph * 16 + p) * 128 + slot];
            a.x += xv.x; a.y += xv.y; a.z += xv.z; a.w += xv.w;
        }
        if (ph == 0) va[slot] = a;
        __syncthreads();
        if (ph == 1) {
            float4 o = va[slot];
            o.x += a.x; o.y += a.y; o.z += a.z; o.w += a.w;
            vl4[slot] = o;
        }
        __syncthreads();
    }

    // ---- Phase B: h0[k0..k0+64) = v @ Wgc[:, chunk]; 16 m-groups x 16 float4 k-slots ----
    {
        const float* vlf = reinterpret_cast<const float*>(vl4);
        const float4* Wgc4 = reinterpret_cast<const float4*>(Wgc);
        const int f4 = t & 15;       // k-slot (4 k each)
        const int mg = t >> 4;       // m-group of 32
        float4 acc = {0.f, 0.f, 0.f, 0.f};
        #pragma unroll
        for (int i = 0; i < 32; ++i) {
            const int m = mg * 32 + i;
            const float4 w = Wgc4[m * (N_HID1 / 4) + (k0 >> 2) + f4];
            const float vm = vlf[m];
            acc.x = fmaf(vm, w.x, acc.x);
            acc.y = fmaf(vm, w.y, acc.y);
            acc.z = fmaf(vm, w.z, acc.z);
            acc.w = fmaf(vm, w.w, acc.w);
        }
        smb[mg][f4 * 4 + 0] = acc.x;
        smb[mg][f4 * 4 + 1] = acc.y;
        smb[mg][f4 * 4 + 2] = acc.z;
        smb[mg][f4 * 4 + 3] = acc.w;
        __syncthreads();
        if (t < 64) {
            float s = bgc[k0 + t];
            #pragma unroll
            for (int g = 0; g < 16; ++g) s += smb[g][t];
            hl[t] = leaky(s);
        }
        __syncthreads();
    }

    // ---- Phase C: h1 partial for (jb, kc) ----
    {
        const int j = jb * 256 + t;  // 0..511
        float acc = 0.f;
        #pragma unroll
        for (int k = 0; k < 64; ++k)
            acc = fmaf(hl[k], W1[(k0 + k) * N_HID2 + j], acc);
        h1p[kc * N_HID2 + j] = acc;
    }

    // ---- last-arrive: t0-only release; only the 32nd block pays an acquire ----
    __shared__ int amLast;
    __syncthreads();   // drains h1p stores to L2 (vmcnt(0) before s_barrier)
    if (t == 0) {
        int old = __hip_atomic_fetch_add(cnt, 1, __ATOMIC_RELEASE, __HIP_MEMORY_SCOPE_AGENT);
        amLast = (old == NBLK2 - 1);
    }
    __syncthreads();
    if (!amLast) return;
    if (t == 0)  // ACQUIRE: make all blocks' h1p stores visible, once
        (void)__hip_atomic_load(cnt, __ATOMIC_ACQUIRE, __HIP_MEMORY_SCOPE_AGENT);
    __syncthreads();

    // ---- Phase D: reduce h1 partials, bias+leaky+dropout, dot W2[:,0], +b2 ----
    {
        float term = 0.f;
        #pragma unroll
        for (int rep = 0; rep < 2; ++rep) {
            const int jj = rep * 256 + t;
            float s = b1[jj];
            #pragma unroll
            for (int p = 0; p < 16; ++p) s += h1p[p * N_HID2 + jj];
            float h = leaky(s);
            h = (du0[jj] >= DROP_P) ? h / (1.0f - DROP_P) : 0.f;
            term = fmaf(h, W2[jj], term);
        }
        #pragma unroll
        for (int off = 32; off; off >>= 1) term += __shfl_down(term, off, 64);
        __shared__ float red[4];
        if ((t & 63) == 0) red[t >> 6] = term;
        __syncthreads();
        if (t == 0)
            out[0] = red[0] + red[1] + red[2] + red[3] + b2[0];
    }
}

extern "C" void kernel_launch(void* const* d_in, const int* in_sizes, int n_in,
                              void* d_out, int out_size, void* d_ws, size_t ws_size,
                              hipStream_t stream) {
    const float* x   = (const float*)d_in[0];
    const float* adj = (const float*)d_in[1];  // row 0 = first 8192 floats
    const float* Wgc = (const float*)d_in[2];
    const float* bgc = (const float*)d_in[3];
    const float* W1  = (const float*)d_in[4];
    const float* b1  = (const float*)d_in[5];
    const float* W2  = (const float*)d_in[6];
    const float* b2  = (const float*)d_in[7];
    const float* du  = (const float*)d_in[8];  // row 0 = first 512 floats
    float* out = (float*)d_out;
    float* ws  = (float*)d_ws;

    float* vp  = ws + VP_OFF;
    float* h1p = ws + H1_OFF;
    int*   cnt = (int*)(ws + CNT_OFF);

    k1_adjrow_x<<<dim3(8, 32),   256, 0, stream>>>(x, adj, vp, cnt);
    k23_fused  <<<dim3(NBLK2),   256, 0, stream>>>(vp, Wgc, bgc, W1, b1, W2, b2, du,
                                                   h1p, cnt, out);
}

// Round 10
// 16.270 us; speedup vs baseline: 1.2261x; 1.0177x over previous
//
#include <hip/hip_runtime.h>

// GCNCountry: out = ((leaky(leaky(adj@(x@Wgc)+bgc) @ W1 + b1) * dropmask) @ W2 + b2)[0]
// -> depends ONLY on row 0 of every intermediate. Vector chain:
//    v  = adj[0,:] @ x            (16 MB x-read, K1, 256 blocks -> 32 partials)
//    h0 = v @ Wgc; h1 = leaky(h0+bgc) @ W1; out = dropout(leaky(h1+b1)).W2+b2
//       -> ALL fused in K23 (32 blocks): each block redundantly computes its own
//          64-wide h0 chunk (2x read of L3-resident Wgc, ~free), h1 partial,
//          then t0-only RELEASE fetch_add; last-arriving block finalizes.
//
// FINAL (round 9 = revert to round-6 best, 16.61us measured):
// Cost model from rounds 1-8: harness/graph fixed overhead ~10-12us; in-graph
// node gap ~1us; K1 ~2.5-3us (16MB stream, near BW limit); K23 ~3us.
// Measured-and-rejected alternatives: spin grid-barrier (+10us, R3);
// deep-k few-block kernels (latency-bound, R4); per-thread agent fences
// (R5); register mega-preloads (neutral, R7); 64 small blocks (worse vp
// reuse + serial reduces, R8). This 2-node shape is the structural floor.

constexpr int N_FEAT  = 512;
constexpr int N_HID1  = 1024;
constexpr int N_HID2  = 512;
constexpr float SLOPE  = 0.01f;
constexpr float DROP_P = 0.3f;

constexpr int VP_N   = 32;      // v partials [32][512]
constexpr int VP_OFF = 0;
constexpr int H1_OFF = 16384;   // h1 partials [16][512]
constexpr int CNT_OFF = 24576;  // 1 int, zeroed by K1 each call
constexpr int NBLK2  = 32;      // K23 grid

__device__ __forceinline__ float leaky(float x) { return x >= 0.f ? x : SLOPE * x; }

// ---------------- K1: v_part[rb][c] = sum_{rows in chunk rb} adj0[row] * x[row][c] ----------------
// grid (8 col-stripes of 64, 32 row-chunks of 256), 256 thr; float4 fully-coalesced x reads.
__global__ __launch_bounds__(256) void k1_adjrow_x(const float* __restrict__ x,
                                                   const float* __restrict__ adj0,
                                                   float* __restrict__ vp,
                                                   int* __restrict__ cnt) {
    const int tid = threadIdx.x;
    if (blockIdx.x == 0 && blockIdx.y == 0 && tid == 0) cnt[0] = 0;  // visible at kernel boundary

    const int f4  = tid & 15;
    const int r   = tid >> 4;          // 0..15
    const int c0  = blockIdx.x * 64;   // col stripe
    const int rb  = blockIdx.y;        // row chunk
    const float4* x4 = reinterpret_cast<const float4*>(x);

    float4 acc = {0.f, 0.f, 0.f, 0.f};
    int row = rb * 256 + r;
    #pragma unroll
    for (int it = 0; it < 16; ++it, row += 16) {
        const float  a  = adj0[row];
        const float4 xv = x4[row * (N_FEAT / 4) + (c0 >> 2) + f4];
        acc.x = fmaf(a, xv.x, acc.x);
        acc.y = fmaf(a, xv.y, acc.y);
        acc.z = fmaf(a, xv.z, acc.z);
        acc.w = fmaf(a, xv.w, acc.w);
    }

    __shared__ float4 sm[256];
    sm[tid] = acc;
    __syncthreads();
    #pragma unroll
    for (int off = 128; off >= 16; off >>= 1) {
        if (tid < off) {
            float4 o = sm[tid + off];
            sm[tid].x += o.x; sm[tid].y += o.y; sm[tid].z += o.z; sm[tid].w += o.w;
        }
        __syncthreads();
    }
    if (tid < 16)
        reinterpret_cast<float4*>(vp + rb * N_FEAT + c0)[tid] = sm[tid];
}

// ---------------- K23: redundant h0 chunk + h1 partial + last-arrive finalize ----------------
// 32 blocks = (jb = bid&1: j-half of 256) x (kc = bid>>1: k-chunk of 64).
__global__ __launch_bounds__(256, 1) void k23_fused(const float* __restrict__ vp,
                                                    const float* __restrict__ Wgc,
                                                    const float* __restrict__ bgc,
                                                    const float* __restrict__ W1,
                                                    const float* __restrict__ b1,
                                                    const float* __restrict__ W2,
                                                    const float* __restrict__ b2,
                                                    const float* __restrict__ du0,
                                                    float* __restrict__ h1p,
                                                    int* __restrict__ cnt,
                                                    float* __restrict__ out) {
    const int t  = threadIdx.x;
    const int jb = blockIdx.x & 1;
    const int kc = blockIdx.x >> 1;
    const int k0 = kc * 64;

    __shared__ float4 vl4[128];      // full v (512 floats)
    __shared__ float4 va[128];       // phase-A scratch
    __shared__ float  hl[64];        // leaky(h0+bgc) chunk
    __shared__ float  smb[16][65];   // phase-B partial reduce (padded)

    // ---- Phase A: v = sum of 32 partials (float4, 2 p-halves, one latency exposure) ----
    {
        const float4* vp4 = reinterpret_cast<const float4*>(vp);
        const int slot = t & 127;
        const int ph   = t >> 7;     // 0,1
        float4 a = {0.f, 0.f, 0.f, 0.f};
        #pragma unroll
        for (int p = 0; p < 16; ++p) {
            const float4 xv = vp4[(ph * 16 + p) * 128 + slot];
            a.x += xv.x; a.y += xv.y; a.z += xv.z; a.w += xv.w;
        }
        if (ph == 0) va[slot] = a;
        __syncthreads();
        if (ph == 1) {
            float4 o = va[slot];
            o.x += a.x; o.y += a.y; o.z += a.z; o.w += a.w;
            vl4[slot] = o;
        }
        __syncthreads();
    }

    // ---- Phase B: h0[k0..k0+64) = v @ Wgc[:, chunk]; 16 m-groups x 16 float4 k-slots ----
    {
        const float* vlf = reinterpret_cast<const float*>(vl4);
        const float4* Wgc4 = reinterpret_cast<const float4*>(Wgc);
        const int f4 = t & 15;       // k-slot (4 k each)
        const int mg = t >> 4;       // m-group of 32
        float4 acc = {0.f, 0.f, 0.f, 0.f};
        #pragma unroll
        for (int i = 0; i < 32; ++i) {
            const int m = mg * 32 + i;
            const float4 w = Wgc4[m * (N_HID1 / 4) + (k0 >> 2) + f4];
            const float vm = vlf[m];
            acc.x = fmaf(vm, w.x, acc.x);
            acc.y = fmaf(vm, w.y, acc.y);
            acc.z = fmaf(vm, w.z, acc.z);
            acc.w = fmaf(vm, w.w, acc.w);
        }
        smb[mg][f4 * 4 + 0] = acc.x;
        smb[mg][f4 * 4 + 1] = acc.y;
        smb[mg][f4 * 4 + 2] = acc.z;
        smb[mg][f4 * 4 + 3] = acc.w;
        __syncthreads();
        if (t < 64) {
            float s = bgc[k0 + t];
            #pragma unroll
            for (int g = 0; g < 16; ++g) s += smb[g][t];
            hl[t] = leaky(s);
        }
        __syncthreads();
    }

    // ---- Phase C: h1 partial for (jb, kc) ----
    {
        const int j = jb * 256 + t;  // 0..511
        float acc = 0.f;
        #pragma unroll
        for (int k = 0; k < 64; ++k)
            acc = fmaf(hl[k], W1[(k0 + k) * N_HID2 + j], acc);
        h1p[kc * N_HID2 + j] = acc;
    }

    // ---- last-arrive: t0-only release; only the 32nd block pays an acquire ----
    __shared__ int amLast;
    __syncthreads();   // drains h1p stores to L2 (vmcnt(0) before s_barrier)
    if (t == 0) {
        int old = __hip_atomic_fetch_add(cnt, 1, __ATOMIC_RELEASE, __HIP_MEMORY_SCOPE_AGENT);
        amLast = (old == NBLK2 - 1);
    }
    __syncthreads();
    if (!amLast) return;
    if (t == 0)  // ACQUIRE: make all blocks' h1p stores visible, once
        (void)__hip_atomic_load(cnt, __ATOMIC_ACQUIRE, __HIP_MEMORY_SCOPE_AGENT);
    __syncthreads();

    // ---- Phase D: reduce h1 partials, bias+leaky+dropout, dot W2[:,0], +b2 ----
    {
        float term = 0.f;
        #pragma unroll
        for (int rep = 0; rep < 2; ++rep) {
            const int jj = rep * 256 + t;
            float s = b1[jj];
            #pragma unroll
            for (int p = 0; p < 16; ++p) s += h1p[p * N_HID2 + jj];
            float h = leaky(s);
            h = (du0[jj] >= DROP_P) ? h / (1.0f - DROP_P) : 0.f;
            term = fmaf(h, W2[jj], term);
        }
        #pragma unroll
        for (int off = 32; off; off >>= 1) term += __shfl_down(term, off, 64);
        __shared__ float red[4];
        if ((t & 63) == 0) red[t >> 6] = term;
        __syncthreads();
        if (t == 0)
            out[0] = red[0] + red[1] + red[2] + red[3] + b2[0];
    }
}

extern "C" void kernel_launch(void* const* d_in, const int* in_sizes, int n_in,
                              void* d_out, int out_size, void* d_ws, size_t ws_size,
                              hipStream_t stream) {
    const float* x   = (const float*)d_in[0];
    const float* adj = (const float*)d_in[1];  // row 0 = first 8192 floats
    const float* Wgc = (const float*)d_in[2];
    const float* bgc = (const float*)d_in[3];
    const float* W1  = (const float*)d_in[4];
    const float* b1  = (const float*)d_in[5];
    const float* W2  = (const float*)d_in[6];
    const float* b2  = (const float*)d_in[7];
    const float* du  = (const float*)d_in[8];  // row 0 = first 512 floats
    float* out = (float*)d_out;
    float* ws  = (float*)d_ws;

    float* vp  = ws + VP_OFF;
    float* h1p = ws + H1_OFF;
    int*   cnt = (int*)(ws + CNT_OFF);

    k1_adjrow_x<<<dim3(8, 32),   256, 0, stream>>>(x, adj, vp, cnt);
    k23_fused  <<<dim3(NBLK2),   256, 0, stream>>>(vp, Wgc, bgc, W1, b1, W2, b2, du,
                                                   h1p, cnt, out);
}